// Round 5
// baseline (136.079 us; speedup 1.0000x reference)
//
#include <hip/hip_runtime.h>

#define NB 8
#define NP 16
#define NS 256
#define NN 4096
#define NBP (NB*NP)             // 128
#define NCHUNK 8
#define CHUNK (NN/NCHUNK)       // 512 n per block
#define NBLK (NBP*NCHUNK)       // 1024
#define EPSV 1e-6f

// ---------------- workspace layout (bytes) ----------------
#define MINW_OFF  0x0            // float[NBLK*NS]  (1 MB)
#define PART_OFF  0x100000       // float[NBLK]
#define S2P_OFF   0x101000       // float[NBP]
#define PP_OFF    0x101200       // float[NBP]
#define CNTA_OFF  0x101400       // uint[NBP]
#define CNTB_OFF  0x101600       // uint

__device__ __forceinline__ float dot4(float4 u, float4 a) {
    return fmaf(u.x, a.x, fmaf(u.y, a.y, fmaf(u.z, a.z, u.w)));
}

__global__ __launch_bounds__(256) void sqreg_all(
    const float* __restrict__ sp,     // (B,P,S,3)
    const float* __restrict__ pts,    // (B,N,3)
    const float* __restrict__ assign, // (B,N,P)
    const float* __restrict__ exist,  // (B,P)
    float* __restrict__ minw,         // (NBLK, S)
    float* __restrict__ partials,     // NBLK
    float* __restrict__ s2p,          // NBP
    float* __restrict__ pp,           // NBP
    unsigned int* __restrict__ cntA,  // NBP
    unsigned int* __restrict__ cntB,
    float* __restrict__ out)
{
    __shared__ float4 lsp[NS];        // (x,y,z,|a|^2)
    __shared__ float4 lpt[CHUNK];     // (-2x,-2y,-2z,|b|^2)
    __shared__ float  pm1[2][CHUNK];  // phase-1 partial mins (per s-half, per n)
    __shared__ float  pm2[4][NS];     // phase-2 partial mins (per n-quarter, per s)
    __shared__ float  psum[4];
    __shared__ float  ppw[4];
    __shared__ float  fin[8];
    __shared__ unsigned int sflag;

    const int bid   = blockIdx.x;
    const int bp    = bid >> 3;       // 0..127
    const int chunk = bid & 7;
    const int p     = bp & 15;
    const int b     = bp >> 4;
    const int tid   = threadIdx.x;
    const int lane  = tid & 63;
    const int wave  = tid >> 6;

    // ---- stage + prescale ----
    {
        const float* s3 = sp + (size_t)(bp*NS)*3;
        float x = s3[tid*3+0], y = s3[tid*3+1], z = s3[tid*3+2];
        lsp[tid] = make_float4(x, y, z, x*x + y*y + z*z);
        const float* q3 = pts + (size_t)(b*NN + chunk*CHUNK)*3;
#pragma unroll
        for (int k = 0; k < 2; ++k) {
            int i = tid + k*256;
            float qx = q3[i*3+0], qy = q3[i*3+1], qz = q3[i*3+2];
            lpt[i] = make_float4(-2.0f*qx, -2.0f*qy, -2.0f*qz, qx*qx + qy*qy + qz*qz);
        }
    }
    __syncthreads();

    // ---- Phase 1: s-half split, 4 n per thread; min over 128 s of (a2 - 2ab) ----
    {
        const int g  = tid >> 7;       // s-half (wave-uniform)
        const int nl = tid & 127;
        float qx[4], qy[4], qz[4], mn[4];
#pragma unroll
        for (int k = 0; k < 4; ++k) {
            float4 q = lpt[nl + k*128];
            qx[k] = q.x; qy[k] = q.y; qz[k] = q.z;
            mn[k] = INFINITY;
        }
        const float4* vs = &lsp[g*128];
#pragma unroll 2
        for (int s = 0; s < 128; s += 2) {
            float4 v0 = vs[s], v1 = vs[s+1];
#pragma unroll
            for (int k = 0; k < 4; ++k) {
                float g0 = fmaf(qx[k], v0.x, fmaf(qy[k], v0.y, fmaf(qz[k], v0.z, v0.w)));
                float g1 = fmaf(qx[k], v1.x, fmaf(qy[k], v1.y, fmaf(qz[k], v1.z, v1.w)));
                mn[k] = fminf(fminf(g0, g1), mn[k]);   // v_min3_f32
            }
        }
#pragma unroll
        for (int k = 0; k < 4; ++k) pm1[g][nl + k*128] = mn[k];
    }

    // ---- Phase 2: 4 s per thread, n-quarter split; min over 128 n of (b2 - 2ab) ----
    {
        const int sg   = tid & 63;
        const int nsub = tid >> 6;     // == wave (uniform)
        float4 a0 = lsp[sg], a1 = lsp[sg+64], a2 = lsp[sg+128], a3 = lsp[sg+192];
        float m0 = INFINITY, m1 = INFINITY, m2 = INFINITY, m3 = INFINITY;
        const float4* us = &lpt[nsub*128];
#pragma unroll 2
        for (int n = 0; n < 128; n += 2) {
            float4 u0 = us[n], u1 = us[n+1];
            m0 = fminf(fminf(dot4(u0,a0), dot4(u1,a0)), m0);
            m1 = fminf(fminf(dot4(u0,a1), dot4(u1,a1)), m1);
            m2 = fminf(fminf(dot4(u0,a2), dot4(u1,a2)), m2);
            m3 = fminf(fminf(dot4(u0,a3), dot4(u1,a3)), m3);
        }
        pm2[nsub][sg]     = m0;
        pm2[nsub][sg+64]  = m1;
        pm2[nsub][sg+128] = m2;
        pm2[nsub][sg+192] = m3;
    }
    __syncthreads();

    // ---- combine phase 2 -> minw (s = tid) ----
    {
        float mm = fminf(fminf(pm2[0][tid], pm2[1][tid]),
                         fminf(pm2[2][tid], pm2[3][tid]));
        minw[(size_t)bid*NS + tid] = fmaxf(mm + lsp[tid].w, 0.0f);
    }

    // ---- combine phase 1 -> weighted partial ----
    float acc = 0.0f;
#pragma unroll
    for (int j = 0; j < 2; ++j) {
        int n = tid + j*256;
        float mm = fminf(pm1[0][n], pm1[1][n]);
        float d  = fmaxf(mm + lpt[n].w, 0.0f);
        acc += d * assign[(size_t)(b*NN + chunk*CHUNK + n)*NP + p];
    }
#pragma unroll
    for (int msk = 32; msk >= 1; msk >>= 1)
        acc += __shfl_xor(acc, msk, 64);
    if (lane == 0) psum[wave] = acc;
    __syncthreads();
    if (tid == 0) partials[bid] = psum[0] + psum[1] + psum[2] + psum[3];

    // ---- gate 1: 8th finisher of this bp does the bp tail ----
    __threadfence();                   // flush minw/partials (all threads)
    __syncthreads();                   // fences complete block-wide
    if (tid == 0) sflag = (atomicAdd(&cntA[bp], 1u) == NCHUNK-1) ? 1u : 0u;
    __syncthreads();
    if (sflag == 0u) return;

    __threadfence();                   // acquire other chunk-blocks' writes
    {
        const float* base = minw + (size_t)(bp*NCHUNK)*NS + tid;
        float m = base[0];
#pragma unroll
        for (int c = 1; c < NCHUNK; ++c) m = fminf(m, base[(size_t)c*NS]);
#pragma unroll
        for (int msk = 32; msk >= 1; msk >>= 1)
            m += __shfl_xor(m, msk, 64);
        if (lane == 0) psum[wave] = m;
    }
    __syncthreads();
    if (tid == 0) {
        s2p[bp] = (psum[0] + psum[1] + psum[2] + psum[3]) * (1.0f/(float)NS);
        float a = 0.0f;
#pragma unroll
        for (int c = 0; c < NCHUNK; ++c) a += partials[bp*NCHUNK + c];
        pp[bp] = a;
    }
    __threadfence();
    __syncthreads();

    // ---- gate 2: 128th finisher does the scalar tail ----
    if (tid == 0) sflag = (atomicAdd(cntB, 1u) == NBP-1) ? 1u : 0u;
    __syncthreads();
    if (sflag == 0u) return;

    __threadfence();                   // acquire all bp tails
    {
        float tsum = (tid < NBP) ? pp[tid] : 0.0f;
#pragma unroll
        for (int msk = 32; msk >= 1; msk >>= 1)
            tsum += __shfl_xor(tsum, msk, 64);
        if (lane == 0) ppw[wave] = tsum;

        if (tid < NBP) {               // waves 0,1 fully active; group of 16 = one b
            float e  = exist[tid];
            float sv = s2p[tid] * e;
#pragma unroll
            for (int msk = 8; msk >= 1; msk >>= 1) {
                e  += __shfl_xor(e,  msk, 64);
                sv += __shfl_xor(sv, msk, 64);
            }
            if ((tid & 15) == 0) fin[tid >> 4] = sv / fmaxf(e, EPSV);
        }
    }
    __syncthreads();
    if (tid == 0) {
        float total = ppw[0] + ppw[1] + ppw[2] + ppw[3];
        float sq = 0.0f;
#pragma unroll
        for (int g = 0; g < NB; ++g) sq += fin[g];
        out[0] = total / (float)(NB*NN) + sq * (1.0f/(float)NB);
    }
}

extern "C" void kernel_launch(void* const* d_in, const int* in_sizes, int n_in,
                              void* d_out, int out_size, void* d_ws, size_t ws_size,
                              hipStream_t stream) {
    const float* sp     = (const float*)d_in[0];
    const float* pts    = (const float*)d_in[1];
    const float* assign = (const float*)d_in[2];
    const float* exist  = (const float*)d_in[3];
    float* out = (float*)d_out;

    char* ws = (char*)d_ws;
    float*        minw = (float*)(ws + MINW_OFF);
    float*        part = (float*)(ws + PART_OFF);
    float*        s2p  = (float*)(ws + S2P_OFF);
    float*        pp   = (float*)(ws + PP_OFF);
    unsigned int* cntA = (unsigned int*)(ws + CNTA_OFF);
    unsigned int* cntB = (unsigned int*)(ws + CNTB_OFF);

    // zero the two gate counters (graph-capturable async memset)
    hipMemsetAsync(ws + CNTA_OFF, 0, (NBP + 1) * sizeof(unsigned int), stream);
    sqreg_all<<<NBLK, 256, 0, stream>>>(sp, pts, assign, exist,
                                        minw, part, s2p, pp, cntA, cntB, out);
}

// Round 6
// 32.483 us; speedup vs baseline: 4.1892x; 4.1892x over previous
//
#include <hip/hip_runtime.h>

#define NB 8
#define NP 16
#define NS 256
#define NN 4096
#define NBP (NB*NP)             // 128
#define NCHUNK 8
#define CHUNK (NN/NCHUNK)       // 512 n per block
#define NBLK (NBP*NCHUNK)       // 1024
#define EPSV 1e-6f

// ---------------- workspace layout (bytes) ----------------
// minw : float[NBLK*NS]  @ 0          (1 MB)
// part : float[NBLK]     @ 0x100000
// s2p  : float[NBP]      @ 0x101000
// pp   : float[NBP]      @ 0x101200

__device__ __forceinline__ float dot4(float4 u, float4 a) {
    return fmaf(u.x, a.x, fmaf(u.y, a.y, fmaf(u.z, a.z, u.w)));
}

__global__ __launch_bounds__(256) void sqreg_main(
    const float* __restrict__ sp,     // (B,P,S,3)
    const float* __restrict__ pts,    // (B,N,3)
    const float* __restrict__ assign, // (B,N,P)
    float* __restrict__ minw,         // (NBLK, S)
    float* __restrict__ partials)     // NBLK
{
    __shared__ float4 lsp[NS];        // (x,y,z,|a|^2)
    __shared__ float4 lpt[CHUNK];     // (-2x,-2y,-2z,|b|^2)
    __shared__ float  pm1[2][CHUNK];  // phase-1 partial mins (s-half, n)
    __shared__ float  pm2[4][NS];     // phase-2 partial mins (n-quarter, s)
    __shared__ float  psum[4];

    const int bid   = blockIdx.x;
    const int bp    = bid >> 3;       // 0..127
    const int chunk = bid & 7;
    const int p     = bp & 15;
    const int b     = bp >> 4;
    const int tid   = threadIdx.x;
    const int lane  = tid & 63;
    const int wave  = tid >> 6;

    // ---- stage + prescale ----
    {
        const float* s3 = sp + (size_t)(bp*NS)*3;
        float x = s3[tid*3+0], y = s3[tid*3+1], z = s3[tid*3+2];
        lsp[tid] = make_float4(x, y, z, x*x + y*y + z*z);
        const float* q3 = pts + (size_t)(b*NN + chunk*CHUNK)*3;
#pragma unroll
        for (int k = 0; k < 2; ++k) {
            int i = tid + k*256;
            float qx = q3[i*3+0], qy = q3[i*3+1], qz = q3[i*3+2];
            lpt[i] = make_float4(-2.0f*qx, -2.0f*qy, -2.0f*qz, qx*qx + qy*qy + qz*qz);
        }
    }
    __syncthreads();

    // ---- Phase 1: s-half split, 4 n per thread; min over 128 s of (a2 - 2ab) ----
    {
        const int g  = tid >> 7;       // s-half (wave-uniform)
        const int nl = tid & 127;
        float qx[4], qy[4], qz[4], mn[4];
#pragma unroll
        for (int k = 0; k < 4; ++k) {
            float4 q = lpt[nl + k*128];
            qx[k] = q.x; qy[k] = q.y; qz[k] = q.z;
            mn[k] = INFINITY;
        }
        const float4* vs = &lsp[g*128];
#pragma unroll 2
        for (int s = 0; s < 128; s += 2) {
            float4 v0 = vs[s], v1 = vs[s+1];
#pragma unroll
            for (int k = 0; k < 4; ++k) {
                float g0 = fmaf(qx[k], v0.x, fmaf(qy[k], v0.y, fmaf(qz[k], v0.z, v0.w)));
                float g1 = fmaf(qx[k], v1.x, fmaf(qy[k], v1.y, fmaf(qz[k], v1.z, v1.w)));
                mn[k] = fminf(fminf(g0, g1), mn[k]);   // v_min3_f32
            }
        }
#pragma unroll
        for (int k = 0; k < 4; ++k) pm1[g][nl + k*128] = mn[k];
    }

    // ---- Phase 2: 4 s per thread, n-quarter split; min over 128 n of (b2 - 2ab) ----
    {
        const int sg   = tid & 63;
        const int nsub = tid >> 6;     // == wave (uniform)
        float4 a0 = lsp[sg], a1 = lsp[sg+64], a2 = lsp[sg+128], a3 = lsp[sg+192];
        float m0 = INFINITY, m1 = INFINITY, m2 = INFINITY, m3 = INFINITY;
        const float4* us = &lpt[nsub*128];
#pragma unroll 2
        for (int n = 0; n < 128; n += 2) {
            float4 u0 = us[n], u1 = us[n+1];
            m0 = fminf(fminf(dot4(u0,a0), dot4(u1,a0)), m0);
            m1 = fminf(fminf(dot4(u0,a1), dot4(u1,a1)), m1);
            m2 = fminf(fminf(dot4(u0,a2), dot4(u1,a2)), m2);
            m3 = fminf(fminf(dot4(u0,a3), dot4(u1,a3)), m3);
        }
        pm2[nsub][sg]     = m0;
        pm2[nsub][sg+64]  = m1;
        pm2[nsub][sg+128] = m2;
        pm2[nsub][sg+192] = m3;
    }
    __syncthreads();

    // ---- combine phase 2 -> minw (s = tid) ----
    {
        float mm = fminf(fminf(pm2[0][tid], pm2[1][tid]),
                         fminf(pm2[2][tid], pm2[3][tid]));
        minw[(size_t)bid*NS + tid] = fmaxf(mm + lsp[tid].w, 0.0f);
    }

    // ---- combine phase 1 -> weighted partial ----
    float acc = 0.0f;
#pragma unroll
    for (int j = 0; j < 2; ++j) {
        int n = tid + j*256;
        float mm = fminf(pm1[0][n], pm1[1][n]);
        float d  = fmaxf(mm + lpt[n].w, 0.0f);
        acc += d * assign[(size_t)(b*NN + chunk*CHUNK + n)*NP + p];
    }
#pragma unroll
    for (int msk = 32; msk >= 1; msk >>= 1)
        acc += __shfl_xor(acc, msk, 64);
    if (lane == 0) psum[wave] = acc;
    __syncthreads();
    if (tid == 0) partials[bid] = psum[0] + psum[1] + psum[2] + psum[3];
}

__global__ __launch_bounds__(256) void sqreg_tail(
    const float* __restrict__ minw,     // (NBLK, S)
    const float* __restrict__ partials, // NBLK
    const float* __restrict__ exist,    // (B,P)
    float* __restrict__ s2p,            // NBP
    float* __restrict__ pp,             // NBP
    float* __restrict__ out)
{
    __shared__ float wsum[4];
    __shared__ float fin[8];
    const int bp   = blockIdx.x;
    const int tid  = threadIdx.x;
    const int lane = tid & 63;
    const int wave = tid >> 6;

    // min over this bp's chunks for s = tid, then sum over s
    const float* base = minw + (size_t)(bp*NCHUNK)*NS + tid;
    float m = base[0];
#pragma unroll
    for (int c = 1; c < NCHUNK; ++c) m = fminf(m, base[(size_t)c*NS]);
#pragma unroll
    for (int msk = 32; msk >= 1; msk >>= 1)
        m += __shfl_xor(m, msk, 64);
    if (lane == 0) wsum[wave] = m;
    __syncthreads();

    if (tid == 0) {
        s2p[bp] = (wsum[0] + wsum[1] + wsum[2] + wsum[3]) * (1.0f/(float)NS);
        float a = 0.0f;
#pragma unroll
        for (int c = 0; c < NCHUNK; ++c) a += partials[bp*NCHUNK + c];
        pp[bp] = a;
    }
    if (bp) return;
    (void)fin;
}

__global__ __launch_bounds__(256) void sqreg_final(
    const float* __restrict__ s2p,
    const float* __restrict__ pp,
    const float* __restrict__ exist,   // (B,P)
    float* __restrict__ out)
{
    __shared__ float ppw[2];
    __shared__ float fin[8];
    const int tid  = threadIdx.x;
    const int lane = tid & 63;

    float tsum = (tid < NBP) ? pp[tid] : 0.0f;
#pragma unroll
    for (int msk = 32; msk >= 1; msk >>= 1)
        tsum += __shfl_xor(tsum, msk, 64);
    if (tid == 0)  ppw[0] = tsum;
    if (tid == 64) ppw[1] = tsum;

    if (tid < NBP) {                   // group of 16 lanes = one b
        float e  = exist[tid];
        float sv = s2p[tid] * e;
#pragma unroll
        for (int msk = 8; msk >= 1; msk >>= 1) {
            e  += __shfl_xor(e,  msk, 64);
            sv += __shfl_xor(sv, msk, 64);
        }
        if ((tid & 15) == 0) fin[tid >> 4] = sv / fmaxf(e, EPSV);
    }
    __syncthreads();

    if (tid == 0) {
        float sq = 0.0f;
#pragma unroll
        for (int g = 0; g < NB; ++g) sq += fin[g];
        out[0] = (ppw[0] + ppw[1]) / (float)(NB*NN) + sq * (1.0f/(float)NB);
    }
    (void)lane;
}

extern "C" void kernel_launch(void* const* d_in, const int* in_sizes, int n_in,
                              void* d_out, int out_size, void* d_ws, size_t ws_size,
                              hipStream_t stream) {
    const float* sp     = (const float*)d_in[0];
    const float* pts    = (const float*)d_in[1];
    const float* assign = (const float*)d_in[2];
    const float* exist  = (const float*)d_in[3];
    float* out = (float*)d_out;

    char* ws = (char*)d_ws;
    float* minw = (float*)(ws);
    float* part = (float*)(ws + 0x100000);
    float* s2p  = (float*)(ws + 0x101000);
    float* pp   = (float*)(ws + 0x101200);

    sqreg_main <<<NBLK, 256, 0, stream>>>(sp, pts, assign, minw, part);
    sqreg_tail <<<NBP,  256, 0, stream>>>(minw, part, exist, s2p, pp, out);
    sqreg_final<<<1,    256, 0, stream>>>(s2p, pp, exist, out);
}

// Round 7
// 31.480 us; speedup vs baseline: 4.3227x; 1.0319x over previous
//
#include <hip/hip_runtime.h>

#define NB 8
#define NP 16
#define NS 256
#define NN 4096
#define NBP (NB*NP)             // 128
#define NCHUNK 8
#define CHUNK (NN/NCHUNK)       // 512 n per block
#define NBLK (NBP*NCHUNK)       // 1024
#define EPSV 1e-6f

// ---------------- workspace layout (bytes) ----------------
// minw : float[NBLK*NS]  @ 0          (1 MB)
// part : float[NBLK]     @ 0x100000
// s2p  : float[NBP]      @ 0x101000
// pp   : float[NBP]      @ 0x101200

__device__ __forceinline__ float dot4(float4 u, float4 a) {
    return fmaf(u.x, a.x, fmaf(u.y, a.y, fmaf(u.z, a.z, u.w)));
}

__global__ __launch_bounds__(256) void sqreg_main(
    const float* __restrict__ sp,     // (B,P,S,3)
    const float* __restrict__ pts,    // (B,N,3)
    const float* __restrict__ assign, // (B,N,P)
    float* __restrict__ minw,         // (NBLK, S)
    float* __restrict__ partials)     // NBLK
{
    __shared__ float4 lsp[NS];        // (x,y,z,|a|^2)
    __shared__ float4 lpt[CHUNK];     // (-2x,-2y,-2z,|b|^2)
    __shared__ float  pm1[4][CHUNK];  // phase-1 partial mins (s-quarter, n)
    __shared__ float  pm2[8][NS];     // phase-2 partial mins (n-eighth, s)
    __shared__ float  psum[4];

    const int bid   = blockIdx.x;
    const int bp    = bid >> 3;       // 0..127
    const int chunk = bid & 7;
    const int p     = bp & 15;
    const int b     = bp >> 4;
    const int tid   = threadIdx.x;
    const int lane  = tid & 63;
    const int wave  = tid >> 6;

    // ---- stage + prescale ----
    {
        const float* s3 = sp + (size_t)(bp*NS)*3;
        float x = s3[tid*3+0], y = s3[tid*3+1], z = s3[tid*3+2];
        lsp[tid] = make_float4(x, y, z, x*x + y*y + z*z);
        const float* q3 = pts + (size_t)(b*NN + chunk*CHUNK)*3;
#pragma unroll
        for (int k = 0; k < 2; ++k) {
            int i = tid + k*256;
            float qx = q3[i*3+0], qy = q3[i*3+1], qz = q3[i*3+2];
            lpt[i] = make_float4(-2.0f*qx, -2.0f*qy, -2.0f*qz, qx*qx + qy*qy + qz*qz);
        }
    }
    __syncthreads();

    // ---- Phase 1: s-quarter split, 8 n per thread; min over 64 s of (a2-2ab) ----
    {
        const int g  = tid >> 6;       // s-quarter, wave-uniform -> broadcast reads
        const int nl = tid & 63;
        float qx[8], qy[8], qz[8], mn[8];
#pragma unroll
        for (int k = 0; k < 8; ++k) {
            float4 q = lpt[nl + k*64];
            qx[k] = q.x; qy[k] = q.y; qz[k] = q.z;
            mn[k] = INFINITY;
        }
        const float4* vs = &lsp[g*64];
#pragma unroll 2
        for (int s = 0; s < 64; s += 2) {
            float4 v0 = vs[s], v1 = vs[s+1];
#pragma unroll
            for (int k = 0; k < 8; ++k) {
                float g0 = fmaf(qx[k], v0.x, fmaf(qy[k], v0.y, fmaf(qz[k], v0.z, v0.w)));
                float g1 = fmaf(qx[k], v1.x, fmaf(qy[k], v1.y, fmaf(qz[k], v1.z, v1.w)));
                mn[k] = fminf(fminf(g0, g1), mn[k]);   // v_min3_f32
            }
        }
#pragma unroll
        for (int k = 0; k < 8; ++k) pm1[g][nl + k*64] = mn[k];
    }

    // ---- Phase 2: 8 s per thread, n-eighth split; min over 64 n of (b2-2ab) ----
    {
        const int sg   = tid & 31;
        const int nsub = tid >> 5;     // 0..7 (2 values per wave -> free 2-way bcast)
        float4 a0 = lsp[sg],       a1 = lsp[sg+32],  a2 = lsp[sg+64],  a3 = lsp[sg+96];
        float4 a4 = lsp[sg+128],   a5 = lsp[sg+160], a6 = lsp[sg+192], a7 = lsp[sg+224];
        float m0=INFINITY,m1=INFINITY,m2=INFINITY,m3=INFINITY;
        float m4=INFINITY,m5=INFINITY,m6=INFINITY,m7=INFINITY;
        const float4* us = &lpt[nsub*64];
#pragma unroll 2
        for (int n = 0; n < 64; n += 2) {
            float4 u0 = us[n], u1 = us[n+1];
            m0 = fminf(fminf(dot4(u0,a0), dot4(u1,a0)), m0);
            m1 = fminf(fminf(dot4(u0,a1), dot4(u1,a1)), m1);
            m2 = fminf(fminf(dot4(u0,a2), dot4(u1,a2)), m2);
            m3 = fminf(fminf(dot4(u0,a3), dot4(u1,a3)), m3);
            m4 = fminf(fminf(dot4(u0,a4), dot4(u1,a4)), m4);
            m5 = fminf(fminf(dot4(u0,a5), dot4(u1,a5)), m5);
            m6 = fminf(fminf(dot4(u0,a6), dot4(u1,a6)), m6);
            m7 = fminf(fminf(dot4(u0,a7), dot4(u1,a7)), m7);
        }
        pm2[nsub][sg]     = m0;  pm2[nsub][sg+32]  = m1;
        pm2[nsub][sg+64]  = m2;  pm2[nsub][sg+96]  = m3;
        pm2[nsub][sg+128] = m4;  pm2[nsub][sg+160] = m5;
        pm2[nsub][sg+192] = m6;  pm2[nsub][sg+224] = m7;
    }
    __syncthreads();

    // ---- combine phase 2 -> minw (s = tid) ----
    {
        float mm = fminf(fminf(fminf(pm2[0][tid], pm2[1][tid]),
                               fminf(pm2[2][tid], pm2[3][tid])),
                         fminf(fminf(pm2[4][tid], pm2[5][tid]),
                               fminf(pm2[6][tid], pm2[7][tid])));
        minw[(size_t)bid*NS + tid] = fmaxf(mm + lsp[tid].w, 0.0f);
    }

    // ---- combine phase 1 -> weighted partial ----
    float acc = 0.0f;
#pragma unroll
    for (int j = 0; j < 2; ++j) {
        int n = tid + j*256;
        float mm = fminf(fminf(pm1[0][n], pm1[1][n]),
                         fminf(pm1[2][n], pm1[3][n]));
        float d  = fmaxf(mm + lpt[n].w, 0.0f);
        acc += d * assign[(size_t)(b*NN + chunk*CHUNK + n)*NP + p];
    }
#pragma unroll
    for (int msk = 32; msk >= 1; msk >>= 1)
        acc += __shfl_xor(acc, msk, 64);
    if (lane == 0) psum[wave] = acc;
    __syncthreads();
    if (tid == 0) partials[bid] = psum[0] + psum[1] + psum[2] + psum[3];
}

__global__ __launch_bounds__(256) void sqreg_tail(
    const float* __restrict__ minw,     // (NBLK, S)
    const float* __restrict__ partials, // NBLK
    float* __restrict__ s2p,            // NBP
    float* __restrict__ pp)             // NBP
{
    __shared__ float wsum[4];
    const int bp   = blockIdx.x;
    const int tid  = threadIdx.x;
    const int lane = tid & 63;
    const int wave = tid >> 6;

    const float* base = minw + (size_t)(bp*NCHUNK)*NS + tid;
    float m = base[0];
#pragma unroll
    for (int c = 1; c < NCHUNK; ++c) m = fminf(m, base[(size_t)c*NS]);
#pragma unroll
    for (int msk = 32; msk >= 1; msk >>= 1)
        m += __shfl_xor(m, msk, 64);
    if (lane == 0) wsum[wave] = m;
    __syncthreads();

    if (tid == 0) {
        s2p[bp] = (wsum[0] + wsum[1] + wsum[2] + wsum[3]) * (1.0f/(float)NS);
        float a = 0.0f;
#pragma unroll
        for (int c = 0; c < NCHUNK; ++c) a += partials[bp*NCHUNK + c];
        pp[bp] = a;
    }
}

__global__ __launch_bounds__(256) void sqreg_final(
    const float* __restrict__ s2p,
    const float* __restrict__ pp,
    const float* __restrict__ exist,   // (B,P)
    float* __restrict__ out)
{
    __shared__ float ppw[2];
    __shared__ float fin[8];
    const int tid = threadIdx.x;

    float tsum = (tid < NBP) ? pp[tid] : 0.0f;
#pragma unroll
    for (int msk = 32; msk >= 1; msk >>= 1)
        tsum += __shfl_xor(tsum, msk, 64);
    if (tid == 0)  ppw[0] = tsum;
    if (tid == 64) ppw[1] = tsum;

    if (tid < NBP) {                   // group of 16 lanes = one b
        float e  = exist[tid];
        float sv = s2p[tid] * e;
#pragma unroll
        for (int msk = 8; msk >= 1; msk >>= 1) {
            e  += __shfl_xor(e,  msk, 64);
            sv += __shfl_xor(sv, msk, 64);
        }
        if ((tid & 15) == 0) fin[tid >> 4] = sv / fmaxf(e, EPSV);
    }
    __syncthreads();

    if (tid == 0) {
        float sq = 0.0f;
#pragma unroll
        for (int g = 0; g < NB; ++g) sq += fin[g];
        out[0] = (ppw[0] + ppw[1]) / (float)(NB*NN) + sq * (1.0f/(float)NB);
    }
}

extern "C" void kernel_launch(void* const* d_in, const int* in_sizes, int n_in,
                              void* d_out, int out_size, void* d_ws, size_t ws_size,
                              hipStream_t stream) {
    const float* sp     = (const float*)d_in[0];
    const float* pts    = (const float*)d_in[1];
    const float* assign = (const float*)d_in[2];
    const float* exist  = (const float*)d_in[3];
    float* out = (float*)d_out;

    char* ws = (char*)d_ws;
    float* minw = (float*)(ws);
    float* part = (float*)(ws + 0x100000);
    float* s2p  = (float*)(ws + 0x101000);
    float* pp   = (float*)(ws + 0x101200);

    sqreg_main <<<NBLK, 256, 0, stream>>>(sp, pts, assign, minw, part);
    sqreg_tail <<<NBP,  256, 0, stream>>>(minw, part, s2p, pp);
    sqreg_final<<<1,    256, 0, stream>>>(s2p, pp, exist, out);
}

// Round 8
// 31.122 us; speedup vs baseline: 4.3725x; 1.0115x over previous
//
#include <hip/hip_runtime.h>

#define NB 8
#define NP 16
#define NS 256
#define NN 4096
#define NBP (NB*NP)             // 128
#define NCHUNK 8
#define CHUNK (NN/NCHUNK)       // 512 n per block
#define NBLK (NBP*NCHUNK)       // 1024
#define EPSV 1e-6f

typedef float f32x2 __attribute__((ext_vector_type(2)));

__device__ __forceinline__ f32x2 pkfma(f32x2 a, f32x2 b, f32x2 c) {
    return __builtin_elementwise_fma(a, b, c);   // -> v_pk_fma_f32 on gfx950
}
__device__ __forceinline__ f32x2 sp2(float v) { return (f32x2){v, v}; }

// ---------------- workspace layout (bytes) ----------------
// minw : float[NBLK*NS]  @ 0          (1 MB)
// part : float[NBLK]     @ 0x100000
// s2p  : float[NBP]      @ 0x101000
// pp   : float[NBP]      @ 0x101200

__global__ __launch_bounds__(256) void sqreg_main(
    const float* __restrict__ sp,     // (B,P,S,3)
    const float* __restrict__ pts,    // (B,N,3)
    const float* __restrict__ assign, // (B,N,P)
    float* __restrict__ minw,         // (NBLK, S)
    float* __restrict__ partials)     // NBLK
{
    // SoA staging: pairs along s / n load as one ds_read_b64 -> feeds v_pk_fma_f32
    __shared__ __align__(16) float lspx[NS], lspy[NS], lspz[NS], lspw[NS];       // a, |a|^2
    __shared__ __align__(16) float lptx[CHUNK], lpty[CHUNK], lptz[CHUNK], lptw[CHUNK]; // -2b, |b|^2
    __shared__ float pm1[4][CHUNK];   // phase-1 partial mins (s-quarter, n)
    __shared__ float pm2[8][NS];      // phase-2 partial mins (n-eighth, s)
    __shared__ float psum[4];

    const int bid   = blockIdx.x;
    const int bp    = bid >> 3;       // 0..127
    const int chunk = bid & 7;
    const int p     = bp & 15;
    const int b     = bp >> 4;
    const int tid   = threadIdx.x;
    const int lane  = tid & 63;
    const int wave  = tid >> 6;

    // ---- stage + prescale (SoA) ----
    {
        const float* s3 = sp + (size_t)(bp*NS)*3;
        float x = s3[tid*3+0], y = s3[tid*3+1], z = s3[tid*3+2];
        lspx[tid] = x; lspy[tid] = y; lspz[tid] = z;
        lspw[tid] = x*x + y*y + z*z;
        const float* q3 = pts + (size_t)(b*NN + chunk*CHUNK)*3;
#pragma unroll
        for (int k = 0; k < 2; ++k) {
            int i = tid + k*256;
            float qx = q3[i*3+0], qy = q3[i*3+1], qz = q3[i*3+2];
            lptx[i] = -2.0f*qx; lpty[i] = -2.0f*qy; lptz[i] = -2.0f*qz;
            lptw[i] = qx*qx + qy*qy + qz*qz;
        }
    }
    __syncthreads();

    // ---- Phase 1: s-quarter split (g==wave), 8 n/thread; min over 64 s of (a2-2ab) ----
    {
        const int g  = tid >> 6;       // wave-uniform -> broadcast b64 reads
        const int nl = tid & 63;
        float qx[8], qy[8], qz[8], mn[8];
#pragma unroll
        for (int k = 0; k < 8; ++k) {
            int i = nl + k*64;
            qx[k] = lptx[i]; qy[k] = lpty[i]; qz[k] = lptz[i];
            mn[k] = INFINITY;
        }
        const int sb = g*64;
#pragma unroll 2
        for (int s = 0; s < 64; s += 2) {
            f32x2 vx = *(const f32x2*)&lspx[sb+s];
            f32x2 vy = *(const f32x2*)&lspy[sb+s];
            f32x2 vz = *(const f32x2*)&lspz[sb+s];
            f32x2 vw = *(const f32x2*)&lspw[sb+s];
#pragma unroll
            for (int k = 0; k < 8; ++k) {
                f32x2 gg = pkfma(sp2(qx[k]), vx,
                           pkfma(sp2(qy[k]), vy,
                           pkfma(sp2(qz[k]), vz, vw)));
                mn[k] = fminf(fminf(gg.x, gg.y), mn[k]);   // v_min3_f32
            }
        }
#pragma unroll
        for (int k = 0; k < 8; ++k) pm1[g][nl + k*64] = mn[k];
    }

    // ---- Phase 2: 8 s/thread, n-eighth split; min over 64 n of (b2-2ab) ----
    {
        const int sg   = tid & 31;
        const int nsub = tid >> 5;     // 0..7 (2 per wave -> 2-way bcast, free)
        float ax[8], ay[8], az[8], m[8];
#pragma unroll
        for (int j = 0; j < 8; ++j) {
            int s = sg + j*32;
            ax[j] = lspx[s]; ay[j] = lspy[s]; az[j] = lspz[s];
            m[j] = INFINITY;
        }
        const int nb = nsub*64;
#pragma unroll 2
        for (int n = 0; n < 64; n += 2) {
            f32x2 ux = *(const f32x2*)&lptx[nb+n];
            f32x2 uy = *(const f32x2*)&lpty[nb+n];
            f32x2 uz = *(const f32x2*)&lptz[nb+n];
            f32x2 uw = *(const f32x2*)&lptw[nb+n];
#pragma unroll
            for (int j = 0; j < 8; ++j) {
                f32x2 gg = pkfma(ux, sp2(ax[j]),
                           pkfma(uy, sp2(ay[j]),
                           pkfma(uz, sp2(az[j]), uw)));
                m[j] = fminf(fminf(gg.x, gg.y), m[j]);     // v_min3_f32
            }
        }
#pragma unroll
        for (int j = 0; j < 8; ++j) pm2[nsub][sg + j*32] = m[j];
    }
    __syncthreads();

    // ---- combine phase 2 -> minw (s = tid) ----
    {
        float mm = fminf(fminf(fminf(pm2[0][tid], pm2[1][tid]),
                               fminf(pm2[2][tid], pm2[3][tid])),
                         fminf(fminf(pm2[4][tid], pm2[5][tid]),
                               fminf(pm2[6][tid], pm2[7][tid])));
        minw[(size_t)bid*NS + tid] = fmaxf(mm + lspw[tid], 0.0f);
    }

    // ---- combine phase 1 -> weighted partial ----
    float acc = 0.0f;
#pragma unroll
    for (int j = 0; j < 2; ++j) {
        int n = tid + j*256;
        float mm = fminf(fminf(pm1[0][n], pm1[1][n]),
                         fminf(pm1[2][n], pm1[3][n]));
        float d  = fmaxf(mm + lptw[n], 0.0f);
        acc += d * assign[(size_t)(b*NN + chunk*CHUNK + n)*NP + p];
    }
#pragma unroll
    for (int msk = 32; msk >= 1; msk >>= 1)
        acc += __shfl_xor(acc, msk, 64);
    if (lane == 0) psum[wave] = acc;
    __syncthreads();
    if (tid == 0) partials[bid] = psum[0] + psum[1] + psum[2] + psum[3];
}

__global__ __launch_bounds__(256) void sqreg_tail(
    const float* __restrict__ minw,     // (NBLK, S)
    const float* __restrict__ partials, // NBLK
    float* __restrict__ s2p,            // NBP
    float* __restrict__ pp)             // NBP
{
    __shared__ float wsum[4];
    const int bp   = blockIdx.x;
    const int tid  = threadIdx.x;
    const int lane = tid & 63;
    const int wave = tid >> 6;

    const float* base = minw + (size_t)(bp*NCHUNK)*NS + tid;
    float m = base[0];
#pragma unroll
    for (int c = 1; c < NCHUNK; ++c) m = fminf(m, base[(size_t)c*NS]);
#pragma unroll
    for (int msk = 32; msk >= 1; msk >>= 1)
        m += __shfl_xor(m, msk, 64);
    if (lane == 0) wsum[wave] = m;
    __syncthreads();

    if (tid == 0) {
        s2p[bp] = (wsum[0] + wsum[1] + wsum[2] + wsum[3]) * (1.0f/(float)NS);
        float a = 0.0f;
#pragma unroll
        for (int c = 0; c < NCHUNK; ++c) a += partials[bp*NCHUNK + c];
        pp[bp] = a;
    }
}

__global__ __launch_bounds__(256) void sqreg_final(
    const float* __restrict__ s2p,
    const float* __restrict__ pp,
    const float* __restrict__ exist,   // (B,P)
    float* __restrict__ out)
{
    __shared__ float ppw[2];
    __shared__ float fin[8];
    const int tid = threadIdx.x;

    float tsum = (tid < NBP) ? pp[tid] : 0.0f;
#pragma unroll
    for (int msk = 32; msk >= 1; msk >>= 1)
        tsum += __shfl_xor(tsum, msk, 64);
    if (tid == 0)  ppw[0] = tsum;
    if (tid == 64) ppw[1] = tsum;

    if (tid < NBP) {                   // group of 16 lanes = one b
        float e  = exist[tid];
        float sv = s2p[tid] * e;
#pragma unroll
        for (int msk = 8; msk >= 1; msk >>= 1) {
            e  += __shfl_xor(e,  msk, 64);
            sv += __shfl_xor(sv, msk, 64);
        }
        if ((tid & 15) == 0) fin[tid >> 4] = sv / fmaxf(e, EPSV);
    }
    __syncthreads();

    if (tid == 0) {
        float sq = 0.0f;
#pragma unroll
        for (int g = 0; g < NB; ++g) sq += fin[g];
        out[0] = (ppw[0] + ppw[1]) / (float)(NB*NN) + sq * (1.0f/(float)NB);
    }
}

extern "C" void kernel_launch(void* const* d_in, const int* in_sizes, int n_in,
                              void* d_out, int out_size, void* d_ws, size_t ws_size,
                              hipStream_t stream) {
    const float* sp     = (const float*)d_in[0];
    const float* pts    = (const float*)d_in[1];
    const float* assign = (const float*)d_in[2];
    const float* exist  = (const float*)d_in[3];
    float* out = (float*)d_out;

    char* ws = (char*)d_ws;
    float* minw = (float*)(ws);
    float* part = (float*)(ws + 0x100000);
    float* s2p  = (float*)(ws + 0x101000);
    float* pp   = (float*)(ws + 0x101200);

    sqreg_main <<<NBLK, 256, 0, stream>>>(sp, pts, assign, minw, part);
    sqreg_tail <<<NBP,  256, 0, stream>>>(minw, part, s2p, pp);
    sqreg_final<<<1,    256, 0, stream>>>(s2p, pp, exist, out);
}